// Round 15
// baseline (1732.814 us; speedup 1.0000x reference)
//
#include <hip/hip_runtime.h>

#define Bz   2
#define Tz   1024
#define Dz   768
#define Hz   12
#define HDz  64
#define Lz   8
#define Vz   32000
#define BTz  (Bz*Tz)       // 2048
#define DFz  (4*Dz)        // 3072
#define PLWz 7077888L      // bf16 elems per layer weight slot
#define NPART 500          // loss partials per row: 250 col-blocks * 2 waves
#define SCALEz 0.036084391824351615f  // 768^-0.5 (reference uses D^-0.5)

typedef __attribute__((ext_vector_type(4))) short s16x4;
typedef __attribute__((ext_vector_type(8))) short s16x8;
typedef __attribute__((ext_vector_type(4))) float f32x4;

__device__ __forceinline__ short f2b(float f) {  // f32 -> bf16 RNE
    union { float f; unsigned u; } v; v.f = f;
    unsigned r = v.u + 0x7fffu + ((v.u >> 16) & 1u);
    return (short)(r >> 16);
}

__device__ __forceinline__ void gload16(const short* g, short* l) {
    __builtin_amdgcn_global_load_lds(
        (const __attribute__((address_space(1))) void*)g,
        (__attribute__((address_space(3))) void*)l, 16, 0, 0);
}

#define MFMA32(a,b,c) __builtin_amdgcn_mfma_f32_16x16x32_bf16(a,b,c,0,0,0)

// ---------------- transpose-convert: f32 [K][N](ldin) -> bf16 [N][K] ----------------
__global__ __launch_bounds__(256)
void tconv_k(const float* __restrict__ in, short* __restrict__ out,
             int K, int N, int ldin)
{
    __shared__ float tl[32][33];
    const int tx = threadIdx.x & 31, ty = threadIdx.x >> 5;
    const int n0 = blockIdx.x * 32, k0 = blockIdx.y * 32;
    #pragma unroll
    for (int i = 0; i < 4; i++)
        tl[ty + i*8][tx] = in[(long)(k0 + ty + i*8)*ldin + n0 + tx];
    __syncthreads();
    #pragma unroll
    for (int i = 0; i < 4; i++)
        out[(long)(n0 + ty + i*8)*K + k0 + tx] = f2b(tl[tx][ty + i*8]);
}

// ---------------- all per-layer weights, one launch ----------------
__global__ __launch_bounds__(256)
void wconv_all(const float* __restrict__ wq, const float* __restrict__ wk,
               const float* __restrict__ wv, const float* __restrict__ wo,
               const float* __restrict__ w1, const float* __restrict__ w2,
               short* __restrict__ wall, int l0)
{
    const int l = l0 + blockIdx.y;
    short* dst = wall + (long)blockIdx.y * PLWz;
    int t = blockIdx.x;
    const float* src; long doff; int K, N, ldin, nx;
    if (t < 2304) {
        int m = t / 576; t -= m * 576;
        src = (m==0 ? wq : m==1 ? wk : m==2 ? wv : wo) + (long)l * 589824;
        doff = (long)m * 589824; K = 768; N = 768; ldin = 768; nx = 24;
    } else if (t < 4608) {
        t -= 2304;
        src = w1 + (long)l * 2359296; doff = 2359296; K = 768; N = 3072; ldin = 3072; nx = 96;
    } else {
        t -= 4608;
        src = w2 + (long)l * 2359296; doff = 4718592; K = 3072; N = 768; ldin = 768; nx = 24;
    }
    const int n0 = (t % nx) * 32, k0 = (t / nx) * 32;
    __shared__ float tl[32][33];
    const int tx = threadIdx.x & 31, ty = threadIdx.x >> 5;
    #pragma unroll
    for (int i = 0; i < 4; i++)
        tl[ty + i*8][tx] = src[(long)(k0 + ty + i*8)*ldin + n0 + tx];
    __syncthreads();
    short* o = dst + doff;
    #pragma unroll
    for (int i = 0; i < 4; i++)
        o[(long)(n0 + ty + i*8)*K + k0 + tx] = f2b(tl[tx][ty + i*8]);
}

// ---------------- generic bf16 GEMM (per-layer), 2-phase double-buffered ----------------
// C[M,N] = epi( A[M,K] @ Bt[N,K]^T ). EPI: 0 none | 1 +bias | 2 +bias+res(f32) | 3 +bias,GELU
template<int BM, int EPI, bool OUTBF>
__global__ __launch_bounds__(256)
void gemm2(const short* __restrict__ A, const short* __restrict__ Bt,
           const float* __restrict__ bias, const float* __restrict__ resp,
           void* __restrict__ Cv, int K, int ldc)
{
    constexpr int BN = 128, BK = 64;
    constexpr int WTM = BM/2;
    constexpr int AM = WTM/16;
    __shared__ short Al[2][BM*BK];
    __shared__ short Bl[2][BN*BK];
    const int bx = blockIdx.x, by = blockIdx.y;
    const int m0 = by*BM, n0 = bx*BN;
    const int tid = threadIdx.x, lane = tid & 63, wid = tid >> 6;
    const int wm = wid >> 1, wn = wid & 1;
    const int r = lane & 15, kg = lane >> 4;
    const int arow = lane >> 3, acol = (lane & 7)*8;

    const short* ga = A  + (long)(m0 + wid*(BM/4) + arow)*K + acol;
    const short* gb = Bt + (long)(n0 + wid*32     + arow)*K + acol;
    const int laoff = (wid*(BM/4))*BK;
    const int lboff = (wid*32)*BK;

    auto stage = [&](int buf, int k0) {
        short* la = &Al[buf][laoff];
        short* lb = &Bl[buf][lboff];
        #pragma unroll
        for (int i = 0; i < BM/32; i++)
            gload16(ga + (long)i*8*K + k0, la + i*8*BK);
        #pragma unroll
        for (int i = 0; i < 4; i++)
            gload16(gb + (long)i*8*K + k0, lb + i*8*BK);
    };

    f32x4 acc[AM][4] = {};
    const int nk = K / BK;

    stage(0, 0);
    __syncthreads();
    int cur = 0;
    for (int t = 0; t < nk; t++) {
        if (t + 1 < nk) stage(cur ^ 1, (t + 1)*BK);
        #pragma unroll
        for (int ks = 0; ks < 2; ks++) {
            s16x8 af[AM], bf[4];
            #pragma unroll
            for (int mI = 0; mI < AM; mI++)
                af[mI] = *(const s16x8*)&Al[cur][(wm*WTM + mI*16 + r)*BK + ks*32 + kg*8];
            #pragma unroll
            for (int nI = 0; nI < 4; nI++)
                bf[nI] = *(const s16x8*)&Bl[cur][(wn*64 + nI*16 + r)*BK + ks*32 + kg*8];
            #pragma unroll
            for (int mI = 0; mI < AM; mI++)
                #pragma unroll
                for (int nI = 0; nI < 4; nI++)
                    acc[mI][nI] = MFMA32(af[mI], bf[nI], acc[mI][nI]);
        }
        __syncthreads();
        cur ^= 1;
    }

    float bnv[4] = {0.f, 0.f, 0.f, 0.f};
    if constexpr (EPI >= 1) {
        #pragma unroll
        for (int nI = 0; nI < 4; nI++) bnv[nI] = bias[n0 + wn*64 + nI*16 + r];
    }

    #pragma unroll
    for (int mI = 0; mI < AM; mI++) {
        #pragma unroll
        for (int nI = 0; nI < 4; nI++) {
            #pragma unroll
            for (int reg = 0; reg < 4; reg++) {
                int row = wm*WTM + mI*16 + kg*4 + reg;
                int col = wn*64 + nI*16 + r;
                long off = (long)(m0+row)*ldc + (n0+col);
                float v = acc[mI][nI][reg] + bnv[nI];
                if constexpr (EPI == 2) v += resp[off];
                if constexpr (EPI == 3) v = 0.5f*v*(1.0f + erff(v*0.70710678118654752f));
                if constexpr (OUTBF) ((short*)Cv)[off] = f2b(v);
                else                 ((float*)Cv)[off] = v;
            }
        }
    }
}

// ---------------- LM-head GEMM (proven r8/r11): BM=256xBN=128, XCD-pinned, fused loss ----
__global__ __launch_bounds__(256, 2)
void gemm_lm(const short* __restrict__ A, const short* __restrict__ Bt,
             const float* __restrict__ bias, float* __restrict__ C,
             float2* __restrict__ part)
{
    constexpr int BM = 256, BN = 128, BK = 64;
    const int b8 = blockIdx.x & 7, rr = blockIdx.x >> 3;   // rr: row-block 0..7
    const int c  = blockIdx.y * 8 + b8;                    // col-block
    if (c >= Vz/BN) return;
    const int m0 = rr * BM, n0 = c * BN;
    const int K = Dz;
    __shared__ short Al[BM*BK];   // 32 KB
    __shared__ short Bl[BN*BK];   // 16 KB
    const int tid = threadIdx.x, lane = tid & 63, wid = tid >> 6;
    const int wm = wid >> 1, wn = wid & 1;
    const int r = lane & 15, kg = lane >> 4;
    const int arow = lane >> 3, acol = (lane & 7)*8;

    const short* ga = A  + (long)(m0 + wid*64 + arow)*K + acol;
    const short* gb = Bt + (long)(n0 + wid*32 + arow)*K + acol;
    short* la = &Al[(wid*64)*BK];
    short* lb = &Bl[(wid*32)*BK];

    f32x4 acc[8][4] = {};

    for (int k0 = 0; k0 < K; k0 += BK) {
        #pragma unroll
        for (int i = 0; i < 8; i++)
            gload16(ga + (long)i*8*K + k0, la + i*8*BK);
        #pragma unroll
        for (int i = 0; i < 4; i++)
            gload16(gb + (long)i*8*K + k0, lb + i*8*BK);
        __syncthreads();
        #pragma unroll
        for (int ks = 0; ks < 2; ks++) {
            s16x8 bf[4];
            #pragma unroll
            for (int nI = 0; nI < 4; nI++)
                bf[nI] = *(const s16x8*)&Bl[(wn*64 + nI*16 + r)*BK + ks*32 + kg*8];
            #pragma unroll
            for (int mI = 0; mI < 8; mI++) {
                s16x8 af = *(const s16x8*)&Al[(wm*128 + mI*16 + r)*BK + ks*32 + kg*8];
                #pragma unroll
                for (int nI = 0; nI < 4; nI++)
                    acc[mI][nI] = MFMA32(af, bf[nI], acc[mI][nI]);
            }
        }
        __syncthreads();
    }

    float bnv[4];
    #pragma unroll
    for (int nI = 0; nI < 4; nI++) bnv[nI] = bias[n0 + wn*64 + nI*16 + r];

    #pragma unroll
    for (int mI = 0; mI < 8; mI++) {
        #pragma unroll
        for (int nI = 0; nI < 4; nI++) {
            #pragma unroll
            for (int reg = 0; reg < 4; reg++) {
                int row = wm*128 + mI*16 + kg*4 + reg;
                int col = wn*64 + nI*16 + r;
                C[(long)(m0+row)*Vz + (n0+col)] = acc[mI][nI][reg] + bnv[nI];
            }
        }
        #pragma unroll
        for (int reg = 0; reg < 4; reg++) {
            float mx = -3.4e38f;
            #pragma unroll
            for (int nI = 0; nI < 4; nI++)
                mx = fmaxf(mx, acc[mI][nI][reg] + bnv[nI]);
            #pragma unroll
            for (int o = 1; o < 16; o <<= 1)
                mx = fmaxf(mx, __shfl_xor(mx, o));
            float s = 0.f;
            #pragma unroll
            for (int nI = 0; nI < 4; nI++)
                s += __expf(acc[mI][nI][reg] + bnv[nI] - mx);
            #pragma unroll
            for (int o = 1; o < 16; o <<= 1)
                s += __shfl_xor(s, o);
            if (r == 0) {
                int row = m0 + wm*128 + mI*16 + kg*4 + reg;
                part[(long)row*NPART + c*2 + wn] = make_float2(mx, s);
            }
        }
    }
}

// ---------------- fused flash attention (scalar-V, proven round-8 optimum) ----------------
__global__ __launch_bounds__(256)
void attn_k(const short* __restrict__ qkv, short* __restrict__ att)
{
    const int w = threadIdx.x >> 6;
    const int lane = threadIdx.x & 63;
    const int r = lane & 15, kg = lane >> 4;
    const int hd0 = blockIdx.y * HDz;
    const long brow = (long)blockIdx.z * Tz;
    const int q0w = blockIdx.x * 64 + w * 16;
    const int qi = q0w + r;

    const short* qp = qkv + (brow + q0w + r) * 2304 + hd0;
    const s16x8 qf0 = *(const s16x8*)(qp + kg*8);
    const s16x8 qf1 = *(const s16x8*)(qp + 32 + kg*8);
    const short* kb = qkv + brow * 2304 + 768 + hd0;
    const short* vb = qkv + brow * 2304 + 1536 + hd0;

    float m = -3.4e38f, l = 0.f;
    f32x4 ot[4] = {};

    const int ntiles = blockIdx.x * 4 + w + 1;
    for (int t = 0; t < ntiles; t++) {
        const int kt = t * 16;
        const short* kp = kb + (long)(kt + r) * 2304;
        s16x8 kf0 = *(const s16x8*)(kp + kg*8);
        s16x8 kf1 = *(const s16x8*)(kp + 32 + kg*8);
        f32x4 z = {};
        f32x4 st = MFMA32(kf0, qf0, z);   // S^T: row=key kt+kg*4+reg, col=q q0w+r
        st = MFMA32(kf1, qf1, st);
        float s4[4];
        #pragma unroll
        for (int j = 0; j < 4; j++) {
            int ki = kt + kg*4 + j;
            s4[j] = (ki <= qi) ? st[j]*SCALEz : -1e30f;
        }
        float cm = fmaxf(fmaxf(s4[0], s4[1]), fmaxf(s4[2], s4[3]));
        cm = fmaxf(cm, __shfl_xor(cm, 16));
        cm = fmaxf(cm, __shfl_xor(cm, 32));
        float mn = fmaxf(m, cm);
        float alpha = __expf(m - mn);
        float p0 = __expf(s4[0]-mn), p1 = __expf(s4[1]-mn);
        float p2 = __expf(s4[2]-mn), p3 = __expf(s4[3]-mn);
        l = l*alpha + (p0+p1+p2+p3);
        m = mn;
        s16x8 pb = { f2b(p0), f2b(p1), f2b(p2), f2b(p3), 0, 0, 0, 0 };
        #pragma unroll
        for (int d0 = 0; d0 < 4; d0++) {
            const short* vp = vb + (long)(kt + kg*4)*2304 + d0*16 + r;
            s16x8 va = { vp[0], vp[2304], vp[4608], vp[6912], 0, 0, 0, 0 };
            f32x4 o = ot[d0];
            o[0]*=alpha; o[1]*=alpha; o[2]*=alpha; o[3]*=alpha;
            ot[d0] = MFMA32(va, pb, o);   // O^T: row d=kg*4+reg, col q=r
        }
    }
    l += __shfl_xor(l, 16);
    l += __shfl_xor(l, 32);
    const float inv = 1.f / l;
    short* ap = att + (brow + q0w + r)*Dz + hd0;
    #pragma unroll
    for (int d0 = 0; d0 < 4; d0++) {
        s16x4 pk = { f2b(ot[d0][0]*inv), f2b(ot[d0][1]*inv),
                     f2b(ot[d0][2]*inv), f2b(ot[d0][3]*inv) };
        *(s16x4*)(ap + d0*16 + kg*4) = pk;
    }
}

// ---------------- embedding ----------------
__global__ void embed_k(const int* __restrict__ idx, const float* __restrict__ tok,
                        const float* __restrict__ pos, float* __restrict__ x)
{
    int qi = blockIdx.x*blockDim.x + threadIdx.x;
    if (qi >= BTz*(Dz/4)) return;
    int row = qi / (Dz/4);
    int c   = (qi % (Dz/4)) * 4;
    int token = idx[row];
    int tpos  = row & (Tz-1);
    float4 a = *reinterpret_cast<const float4*>(tok + (long)token*Dz + c);
    float4 p = *reinterpret_cast<const float4*>(pos + (long)tpos*Dz + c);
    float4 o; o.x=a.x+p.x; o.y=a.y+p.y; o.z=a.z+p.z; o.w=a.w+p.w;
    *reinterpret_cast<float4*>(x + (long)row*Dz + c) = o;
}

// ---------------- layernorm: wave per row, f32 in, bf16 out ----------------
__global__ __launch_bounds__(256)
void ln_k(const float* __restrict__ x, const float* __restrict__ w,
          const float* __restrict__ b, short* __restrict__ y)
{
    const int lane = threadIdx.x & 63;
    const int row = blockIdx.x*4 + (threadIdx.x >> 6);
    const float* xr = x + (long)row*Dz;
    float4 v[3];
    #pragma unroll
    for (int j = 0; j < 3; j++) v[j] = *(const float4*)(xr + lane*4 + j*256);
    float s = 0.f, ss = 0.f;
    #pragma unroll
    for (int j = 0; j < 3; j++) {
        s  += v[j].x + v[j].y + v[j].z + v[j].w;
        ss += v[j].x*v[j].x + v[j].y*v[j].y + v[j].z*v[j].z + v[j].w*v[j].w;
    }
    #pragma unroll
    for (int o = 32; o > 0; o >>= 1) {
        s += __shfl_xor(s, o); ss += __shfl_xor(ss, o);
    }
    float mean = s * (1.0f/Dz);
    float var  = ss * (1.0f/Dz) - mean*mean;
    float rs = rsqrtf(var + 1e-5f);
    short* yr = y + (long)row*Dz;
    #pragma unroll
    for (int j = 0; j < 3; j++) {
        float4 wj = *(const float4*)(w + lane*4 + j*256);
        float4 bj = *(const float4*)(b + lane*4 + j*256);
        s16x4 pk = { f2b((v[j].x-mean)*rs*wj.x + bj.x),
                     f2b((v[j].y-mean)*rs*wj.y + bj.y),
                     f2b((v[j].z-mean)*rs*wj.z + bj.z),
                     f2b((v[j].w-mean)*rs*wj.w + bj.w) };
        *(s16x4*)(yr + lane*4 + j*256) = pk;
    }
}

// ---------------- loss from fused partials ----------------
__global__ __launch_bounds__(256)
void lossfin_k(const float* __restrict__ logits, const float2* __restrict__ part,
               const int* __restrict__ tgt, float* __restrict__ row_loss)
{
    const int row = blockIdx.x, t = threadIdx.x;
    float m = -3.4e38f, s = 0.f;
    for (int i = t; i < NPART; i += 256) {
        float2 p = part[(long)row*NPART + i];
        float M = fmaxf(m, p.x);
        s = s*__expf(m - M) + p.y*__expf(p.x - M);
        m = M;
    }
    __shared__ float smm[256], sms[256];
    smm[t] = m; sms[t] = s; __syncthreads();
    for (int k = 128; k > 0; k >>= 1) {
        if (t < k) {
            float M = fmaxf(smm[t], smm[t+k]);
            sms[t] = sms[t]*__expf(smm[t]-M) + sms[t+k]*__expf(smm[t+k]-M);
            smm[t] = M;
        }
        __syncthreads();
    }
    if (t == 0)
        row_loss[row] = smm[0] + logf(sms[0]) - logits[(long)row*Vz + tgt[row]];
}

// ---------------- fallback two-pass loss ----------------
__global__ __launch_bounds__(256)
void loss_rows_k(const float* __restrict__ logits, const int* __restrict__ tgt,
                 float* __restrict__ row_loss)
{
    int row = blockIdx.x;
    const float* lr = logits + (long)row*Vz;
    const float4* lr4 = (const float4*)lr;
    int t = threadIdx.x;
    __shared__ float sm[256];
    float mx = -3.4e38f;
    for (int c = t; c < Vz/4; c += 256) {
        float4 f = lr4[c];
        mx = fmaxf(mx, fmaxf(fmaxf(f.x, f.y), fmaxf(f.z, f.w)));
    }
    sm[t] = mx; __syncthreads();
    for (int k = 128; k > 0; k >>= 1) { if (t < k) sm[t] = fmaxf(sm[t], sm[t+k]); __syncthreads(); }
    float m = sm[0]; __syncthreads();
    float s = 0.f;
    for (int c = t; c < Vz/4; c += 256) {
        float4 f = lr4[c];
        s += expf(f.x-m) + expf(f.y-m) + expf(f.z-m) + expf(f.w-m);
    }
    sm[t] = s; __syncthreads();
    for (int k = 128; k > 0; k >>= 1) { if (t < k) sm[t] += sm[t+k]; __syncthreads(); }
    if (t == 0) {
        float logZ = m + logf(sm[0]);
        row_loss[row] = logZ - lr[tgt[row]];
    }
}

__global__ void loss_reduce_k(const float* __restrict__ row_loss, float* __restrict__ out)
{
    __shared__ float sm[256];
    int t = threadIdx.x;
    float s = 0.f;
    for (int i = t; i < BTz; i += 256) s += row_loss[i];
    sm[t] = s; __syncthreads();
    for (int k = 128; k > 0; k >>= 1) { if (t < k) sm[t] += sm[t+k]; __syncthreads(); }
    if (t == 0) out[0] = sm[0] * (1.0f/BTz);
}

// ---------------- host ----------------
extern "C" void kernel_launch(void* const* d_in, const int* in_sizes, int n_in,
                              void* d_out, int out_size, void* d_ws, size_t ws_size,
                              hipStream_t stream)
{
    const int*   idx     = (const int*)  d_in[0];
    const int*   tgt     = (const int*)  d_in[1];
    const float* tok_emb = (const float*)d_in[2];
    const float* pos_emb = (const float*)d_in[3];
    const float* ln1_w   = (const float*)d_in[4];
    const float* ln1_b   = (const float*)d_in[5];
    const float* wq      = (const float*)d_in[6];
    const float* wk      = (const float*)d_in[7];
    const float* wv      = (const float*)d_in[8];
    const float* wo      = (const float*)d_in[9];
    const float* bo      = (const float*)d_in[10];
    const float* ln2_w   = (const float*)d_in[11];
    const float* ln2_b   = (const float*)d_in[12];
    const float* w1      = (const float*)d_in[13];
    const float* b1      = (const float*)d_in[14];
    const float* w2      = (const float*)d_in[15];
    const float* b2      = (const float*)d_in[16];
    const float* lnf_w   = (const float*)d_in[17];
    const float* lnf_b   = (const float*)d_in[18];
    const float* lm_w    = (const float*)d_in[19];
    const float* lm_b    = (const float*)d_in[20];

    float* logits = (float*)d_out;
    float* loss   = logits + (long)BTz*Vz;

    char* p = (char*)d_ws;
    float*  x     = (float*)p;  p += (long)BTz*Dz*4;
    float*  rloss = (float*)p;  p += BTz*4;
    float2* part  = (float2*)p; p += (long)BTz*NPART*8;
    short*  h     = (short*)p;  p += (long)BTz*Dz*2;
    short*  qkvb  = (short*)p;  p += (long)BTz*2304*2;
    short*  attb  = (short*)p;  p += (long)BTz*Dz*2;
    short*  midb  = (short*)p;  p += (long)BTz*DFz*2;
    short*  wall  = (short*)p;
    size_t fixed = (size_t)(p - (char*)d_ws);
    const long LMT = (long)Vz*Dz;                       // 24,576,000
    bool upfront = ws_size >= fixed + (size_t)(8*PLWz + LMT)*2;
    short* lmt = wall + (upfront ? 8*PLWz : PLWz);

    embed_k<<<dim3((BTz*(Dz/4) + 255)/256), 256, 0, stream>>>(idx, tok_emb, pos_emb, x);

    if (upfront) {
        wconv_all<<<dim3(6912, 8), 256, 0, stream>>>(wq, wk, wv, wo, w1, w2, wall, 0);
        tconv_k<<<dim3(Vz/32, 24), 256, 0, stream>>>(lm_w, lmt, Dz, Vz, Vz);
    }

    for (int l = 0; l < Lz; l++) {
        short* wl = wall + (upfront ? (long)l*PLWz : 0);
        if (!upfront)
            wconv_all<<<dim3(6912, 1), 256, 0, stream>>>(wq, wk, wv, wo, w1, w2, wall, l);

        ln_k<<<BTz/4, 256, 0, stream>>>(x, ln1_w + l*Dz, ln1_b + l*Dz, h);
        gemm2<32,0,true><<<dim3(18,64), 256, 0, stream>>>(
            h, wl, nullptr, nullptr, qkvb, Dz, 2304);
        attn_k<<<dim3(Tz/64, Hz, Bz), 256, 0, stream>>>(qkvb, attb);
        gemm2<32,2,false><<<dim3(6,64), 256, 0, stream>>>(
            attb, wl + 1769472, bo + l*Dz, x, x, Dz, Dz);
        ln_k<<<BTz/4, 256, 0, stream>>>(x, ln2_w + l*Dz, ln2_b + l*Dz, h);
        gemm2<32,3,true><<<dim3(24,64), 256, 0, stream>>>(
            h, wl + 2359296, b1 + l*DFz, nullptr, midb, Dz, DFz);
        gemm2<32,2,false><<<dim3(6,64), 256, 0, stream>>>(
            midb, wl + 4718592, b2 + l*Dz, x, x, DFz, Dz);
    }

    ln_k<<<BTz/4, 256, 0, stream>>>(x, lnf_w, lnf_b, h);
    if (upfront) {
        gemm_lm<<<dim3(64, 32), 256, 0, stream>>>(h, lmt, lm_b, logits, part);
        lossfin_k<<<BTz, 256, 0, stream>>>(logits, part, tgt, rloss);
    } else {
        for (int c = 0; c < Vz; c += 8192) {
            int cn = (Vz - c < 8192) ? (Vz - c) : 8192;
            tconv_k<<<dim3(cn/32, 24), 256, 0, stream>>>(lm_w + c, lmt, Dz, cn, Vz);
            gemm2<128,1,false><<<dim3(cn/128, 16), 256, 0, stream>>>(
                h, lmt, lm_b + c, nullptr, logits + c, Dz, Vz);
        }
        loss_rows_k<<<BTz, 256, 0, stream>>>(logits, tgt, rloss);
    }
    loss_reduce_k<<<1, 256, 0, stream>>>(rloss, loss);
}

// Round 16
// 1610.513 us; speedup vs baseline: 1.0759x; 1.0759x over previous
//
#include <hip/hip_runtime.h>

#define Bz   2
#define Tz   1024
#define Dz   768
#define Hz   12
#define HDz  64
#define Lz   8
#define Vz   32000
#define BTz  (Bz*Tz)       // 2048
#define DFz  (4*Dz)        // 3072
#define PLWz 7077888L      // bf16 elems per layer weight slot
#define NPART 500          // loss partials per row: 250 col-blocks * 2 waves
#define SCALEz 0.036084391824351615f  // 768^-0.5 (reference uses D^-0.5)

typedef __attribute__((ext_vector_type(4))) short s16x4;
typedef __attribute__((ext_vector_type(8))) short s16x8;
typedef __attribute__((ext_vector_type(4))) float f32x4;

__device__ __forceinline__ short f2b(float f) {  // f32 -> bf16 RNE
    union { float f; unsigned u; } v; v.f = f;
    unsigned r = v.u + 0x7fffu + ((v.u >> 16) & 1u);
    return (short)(r >> 16);
}

__device__ __forceinline__ void gload16(const short* g, short* l) {
    __builtin_amdgcn_global_load_lds(
        (const __attribute__((address_space(1))) void*)g,
        (__attribute__((address_space(3))) void*)l, 16, 0, 0);
}

#define MFMA32(a,b,c) __builtin_amdgcn_mfma_f32_16x16x32_bf16(a,b,c,0,0,0)

// ---------------- transpose-convert: f32 [K][N](ldin) -> bf16 [N][K] ----------------
__global__ __launch_bounds__(256)
void tconv_k(const float* __restrict__ in, short* __restrict__ out,
             int K, int N, int ldin)
{
    __shared__ float tl[32][33];
    const int tx = threadIdx.x & 31, ty = threadIdx.x >> 5;
    const int n0 = blockIdx.x * 32, k0 = blockIdx.y * 32;
    #pragma unroll
    for (int i = 0; i < 4; i++)
        tl[ty + i*8][tx] = in[(long)(k0 + ty + i*8)*ldin + n0 + tx];
    __syncthreads();
    #pragma unroll
    for (int i = 0; i < 4; i++)
        out[(long)(n0 + ty + i*8)*K + k0 + tx] = f2b(tl[tx][ty + i*8]);
}

// ---------------- all per-layer weights, one launch ----------------
__global__ __launch_bounds__(256)
void wconv_all(const float* __restrict__ wq, const float* __restrict__ wk,
               const float* __restrict__ wv, const float* __restrict__ wo,
               const float* __restrict__ w1, const float* __restrict__ w2,
               short* __restrict__ wall, int l0)
{
    const int l = l0 + blockIdx.y;
    short* dst = wall + (long)blockIdx.y * PLWz;
    int t = blockIdx.x;
    const float* src; long doff; int K, N, ldin, nx;
    if (t < 2304) {
        int m = t / 576; t -= m * 576;
        src = (m==0 ? wq : m==1 ? wk : m==2 ? wv : wo) + (long)l * 589824;
        doff = (long)m * 589824; K = 768; N = 768; ldin = 768; nx = 24;
    } else if (t < 4608) {
        t -= 2304;
        src = w1 + (long)l * 2359296; doff = 2359296; K = 768; N = 3072; ldin = 3072; nx = 96;
    } else {
        t -= 4608;
        src = w2 + (long)l * 2359296; doff = 4718592; K = 3072; N = 768; ldin = 768; nx = 24;
    }
    const int n0 = (t % nx) * 32, k0 = (t / nx) * 32;
    __shared__ float tl[32][33];
    const int tx = threadIdx.x & 31, ty = threadIdx.x >> 5;
    #pragma unroll
    for (int i = 0; i < 4; i++)
        tl[ty + i*8][tx] = src[(long)(k0 + ty + i*8)*ldin + n0 + tx];
    __syncthreads();
    short* o = dst + doff;
    #pragma unroll
    for (int i = 0; i < 4; i++)
        o[(long)(n0 + ty + i*8)*K + k0 + tx] = f2b(tl[tx][ty + i*8]);
}

// ---------------- generic bf16 GEMM (per-layer), 2-phase double-buffered ----------------
// C[M,N] = epi( A[M,K] @ Bt[N,K]^T ). EPI: 0 none | 1 +bias | 2 +bias+res(f32) | 3 +bias,GELU
template<int BM, int EPI, bool OUTBF>
__global__ __launch_bounds__(256)
void gemm2(const short* __restrict__ A, const short* __restrict__ Bt,
           const float* __restrict__ bias, const float* __restrict__ resp,
           void* __restrict__ Cv, int K, int ldc)
{
    constexpr int BN = 128, BK = 64;
    constexpr int WTM = BM/2;
    constexpr int AM = WTM/16;
    __shared__ short Al[2][BM*BK];
    __shared__ short Bl[2][BN*BK];
    const int bx = blockIdx.x, by = blockIdx.y;
    const int m0 = by*BM, n0 = bx*BN;
    const int tid = threadIdx.x, lane = tid & 63, wid = tid >> 6;
    const int wm = wid >> 1, wn = wid & 1;
    const int r = lane & 15, kg = lane >> 4;
    const int arow = lane >> 3, acol = (lane & 7)*8;

    const short* ga = A  + (long)(m0 + wid*(BM/4) + arow)*K + acol;
    const short* gb = Bt + (long)(n0 + wid*32     + arow)*K + acol;
    const int laoff = (wid*(BM/4))*BK;
    const int lboff = (wid*32)*BK;

    auto stage = [&](int buf, int k0) {
        short* la = &Al[buf][laoff];
        short* lb = &Bl[buf][lboff];
        #pragma unroll
        for (int i = 0; i < BM/32; i++)
            gload16(ga + (long)i*8*K + k0, la + i*8*BK);
        #pragma unroll
        for (int i = 0; i < 4; i++)
            gload16(gb + (long)i*8*K + k0, lb + i*8*BK);
    };

    f32x4 acc[AM][4] = {};
    const int nk = K / BK;

    stage(0, 0);
    __syncthreads();
    int cur = 0;
    for (int t = 0; t < nk; t++) {
        if (t + 1 < nk) stage(cur ^ 1, (t + 1)*BK);
        #pragma unroll
        for (int ks = 0; ks < 2; ks++) {
            s16x8 af[AM], bf[4];
            #pragma unroll
            for (int mI = 0; mI < AM; mI++)
                af[mI] = *(const s16x8*)&Al[cur][(wm*WTM + mI*16 + r)*BK + ks*32 + kg*8];
            #pragma unroll
            for (int nI = 0; nI < 4; nI++)
                bf[nI] = *(const s16x8*)&Bl[cur][(wn*64 + nI*16 + r)*BK + ks*32 + kg*8];
            #pragma unroll
            for (int mI = 0; mI < AM; mI++)
                #pragma unroll
                for (int nI = 0; nI < 4; nI++)
                    acc[mI][nI] = MFMA32(af[mI], bf[nI], acc[mI][nI]);
        }
        __syncthreads();
        cur ^= 1;
    }

    float bnv[4] = {0.f, 0.f, 0.f, 0.f};
    if constexpr (EPI >= 1) {
        #pragma unroll
        for (int nI = 0; nI < 4; nI++) bnv[nI] = bias[n0 + wn*64 + nI*16 + r];
    }

    #pragma unroll
    for (int mI = 0; mI < AM; mI++) {
        #pragma unroll
        for (int nI = 0; nI < 4; nI++) {
            #pragma unroll
            for (int reg = 0; reg < 4; reg++) {
                int row = wm*WTM + mI*16 + kg*4 + reg;
                int col = wn*64 + nI*16 + r;
                long off = (long)(m0+row)*ldc + (n0+col);
                float v = acc[mI][nI][reg] + bnv[nI];
                if constexpr (EPI == 2) v += resp[off];
                if constexpr (EPI == 3) v = 0.5f*v*(1.0f + erff(v*0.70710678118654752f));
                if constexpr (OUTBF) ((short*)Cv)[off] = f2b(v);
                else                 ((float*)Cv)[off] = v;
            }
        }
    }
}

// ---------------- LM-head GEMM (proven r8/r11): BM=256xBN=128, XCD-pinned, fused loss ----
__global__ __launch_bounds__(256, 2)
void gemm_lm(const short* __restrict__ A, const short* __restrict__ Bt,
             const float* __restrict__ bias, float* __restrict__ C,
             float2* __restrict__ part)
{
    constexpr int BM = 256, BN = 128, BK = 64;
    const int b8 = blockIdx.x & 7, rr = blockIdx.x >> 3;   // rr: row-block 0..7
    const int c  = blockIdx.y * 8 + b8;                    // col-block
    if (c >= Vz/BN) return;
    const int m0 = rr * BM, n0 = c * BN;
    const int K = Dz;
    __shared__ short Al[BM*BK];   // 32 KB
    __shared__ short Bl[BN*BK];   // 16 KB
    const int tid = threadIdx.x, lane = tid & 63, wid = tid >> 6;
    const int wm = wid >> 1, wn = wid & 1;
    const int r = lane & 15, kg = lane >> 4;
    const int arow = lane >> 3, acol = (lane & 7)*8;

    const short* ga = A  + (long)(m0 + wid*64 + arow)*K + acol;
    const short* gb = Bt + (long)(n0 + wid*32 + arow)*K + acol;
    short* la = &Al[(wid*64)*BK];
    short* lb = &Bl[(wid*32)*BK];

    f32x4 acc[8][4] = {};

    for (int k0 = 0; k0 < K; k0 += BK) {
        #pragma unroll
        for (int i = 0; i < 8; i++)
            gload16(ga + (long)i*8*K + k0, la + i*8*BK);
        #pragma unroll
        for (int i = 0; i < 4; i++)
            gload16(gb + (long)i*8*K + k0, lb + i*8*BK);
        __syncthreads();
        #pragma unroll
        for (int ks = 0; ks < 2; ks++) {
            s16x8 bf[4];
            #pragma unroll
            for (int nI = 0; nI < 4; nI++)
                bf[nI] = *(const s16x8*)&Bl[(wn*64 + nI*16 + r)*BK + ks*32 + kg*8];
            #pragma unroll
            for (int mI = 0; mI < 8; mI++) {
                s16x8 af = *(const s16x8*)&Al[(wm*128 + mI*16 + r)*BK + ks*32 + kg*8];
                #pragma unroll
                for (int nI = 0; nI < 4; nI++)
                    acc[mI][nI] = MFMA32(af, bf[nI], acc[mI][nI]);
            }
        }
        __syncthreads();
    }

    float bnv[4];
    #pragma unroll
    for (int nI = 0; nI < 4; nI++) bnv[nI] = bias[n0 + wn*64 + nI*16 + r];

    #pragma unroll
    for (int mI = 0; mI < 8; mI++) {
        #pragma unroll
        for (int nI = 0; nI < 4; nI++) {
            #pragma unroll
            for (int reg = 0; reg < 4; reg++) {
                int row = wm*128 + mI*16 + kg*4 + reg;
                int col = wn*64 + nI*16 + r;
                C[(long)(m0+row)*Vz + (n0+col)] = acc[mI][nI][reg] + bnv[nI];
            }
        }
        #pragma unroll
        for (int reg = 0; reg < 4; reg++) {
            float mx = -3.4e38f;
            #pragma unroll
            for (int nI = 0; nI < 4; nI++)
                mx = fmaxf(mx, acc[mI][nI][reg] + bnv[nI]);
            #pragma unroll
            for (int o = 1; o < 16; o <<= 1)
                mx = fmaxf(mx, __shfl_xor(mx, o));
            float s = 0.f;
            #pragma unroll
            for (int nI = 0; nI < 4; nI++)
                s += __expf(acc[mI][nI][reg] + bnv[nI] - mx);
            #pragma unroll
            for (int o = 1; o < 16; o <<= 1)
                s += __shfl_xor(s, o);
            if (r == 0) {
                int row = m0 + wm*128 + mI*16 + kg*4 + reg;
                part[(long)row*NPART + c*2 + wn] = make_float2(mx, s);
            }
        }
    }
}

// ---------------- fused flash attention (scalar-V, proven round-8 optimum) ----------------
__global__ __launch_bounds__(256)
void attn_k(const short* __restrict__ qkv, short* __restrict__ att)
{
    const int w = threadIdx.x >> 6;
    const int lane = threadIdx.x & 63;
    const int r = lane & 15, kg = lane >> 4;
    const int hd0 = blockIdx.y * HDz;
    const long brow = (long)blockIdx.z * Tz;
    const int q0w = blockIdx.x * 64 + w * 16;
    const int qi = q0w + r;

    const short* qp = qkv + (brow + q0w + r) * 2304 + hd0;
    const s16x8 qf0 = *(const s16x8*)(qp + kg*8);
    const s16x8 qf1 = *(const s16x8*)(qp + 32 + kg*8);
    const short* kb = qkv + brow * 2304 + 768 + hd0;
    const short* vb = qkv + brow * 2304 + 1536 + hd0;

    float m = -3.4e38f, l = 0.f;
    f32x4 ot[4] = {};

    const int ntiles = blockIdx.x * 4 + w + 1;
    for (int t = 0; t < ntiles; t++) {
        const int kt = t * 16;
        const short* kp = kb + (long)(kt + r) * 2304;
        s16x8 kf0 = *(const s16x8*)(kp + kg*8);
        s16x8 kf1 = *(const s16x8*)(kp + 32 + kg*8);
        f32x4 z = {};
        f32x4 st = MFMA32(kf0, qf0, z);   // S^T: row=key kt+kg*4+reg, col=q q0w+r
        st = MFMA32(kf1, qf1, st);
        float s4[4];
        #pragma unroll
        for (int j = 0; j < 4; j++) {
            int ki = kt + kg*4 + j;
            s4[j] = (ki <= qi) ? st[j]*SCALEz : -1e30f;
        }
        float cm = fmaxf(fmaxf(s4[0], s4[1]), fmaxf(s4[2], s4[3]));
        cm = fmaxf(cm, __shfl_xor(cm, 16));
        cm = fmaxf(cm, __shfl_xor(cm, 32));
        float mn = fmaxf(m, cm);
        float alpha = __expf(m - mn);
        float p0 = __expf(s4[0]-mn), p1 = __expf(s4[1]-mn);
        float p2 = __expf(s4[2]-mn), p3 = __expf(s4[3]-mn);
        l = l*alpha + (p0+p1+p2+p3);
        m = mn;
        s16x8 pb = { f2b(p0), f2b(p1), f2b(p2), f2b(p3), 0, 0, 0, 0 };
        #pragma unroll
        for (int d0 = 0; d0 < 4; d0++) {
            const short* vp = vb + (long)(kt + kg*4)*2304 + d0*16 + r;
            s16x8 va = { vp[0], vp[2304], vp[4608], vp[6912], 0, 0, 0, 0 };
            f32x4 o = ot[d0];
            o[0]*=alpha; o[1]*=alpha; o[2]*=alpha; o[3]*=alpha;
            ot[d0] = MFMA32(va, pb, o);   // O^T: row d=kg*4+reg, col q=r
        }
    }
    l += __shfl_xor(l, 16);
    l += __shfl_xor(l, 32);
    const float inv = 1.f / l;
    short* ap = att + (brow + q0w + r)*Dz + hd0;
    #pragma unroll
    for (int d0 = 0; d0 < 4; d0++) {
        s16x4 pk = { f2b(ot[d0][0]*inv), f2b(ot[d0][1]*inv),
                     f2b(ot[d0][2]*inv), f2b(ot[d0][3]*inv) };
        *(s16x4*)(ap + d0*16 + kg*4) = pk;
    }
}

// ---------------- embedding ----------------
__global__ void embed_k(const int* __restrict__ idx, const float* __restrict__ tok,
                        const float* __restrict__ pos, float* __restrict__ x)
{
    int qi = blockIdx.x*blockDim.x + threadIdx.x;
    if (qi >= BTz*(Dz/4)) return;
    int row = qi / (Dz/4);
    int c   = (qi % (Dz/4)) * 4;
    int token = idx[row];
    int tpos  = row & (Tz-1);
    float4 a = *reinterpret_cast<const float4*>(tok + (long)token*Dz + c);
    float4 p = *reinterpret_cast<const float4*>(pos + (long)tpos*Dz + c);
    float4 o; o.x=a.x+p.x; o.y=a.y+p.y; o.z=a.z+p.z; o.w=a.w+p.w;
    *reinterpret_cast<float4*>(x + (long)row*Dz + c) = o;
}

// ---------------- layernorm: wave per row, f32 in, bf16 out ----------------
__global__ __launch_bounds__(256)
void ln_k(const float* __restrict__ x, const float* __restrict__ w,
          const float* __restrict__ b, short* __restrict__ y)
{
    const int lane = threadIdx.x & 63;
    const int row = blockIdx.x*4 + (threadIdx.x >> 6);
    const float* xr = x + (long)row*Dz;
    float4 v[3];
    #pragma unroll
    for (int j = 0; j < 3; j++) v[j] = *(const float4*)(xr + lane*4 + j*256);
    float s = 0.f, ss = 0.f;
    #pragma unroll
    for (int j = 0; j < 3; j++) {
        s  += v[j].x + v[j].y + v[j].z + v[j].w;
        ss += v[j].x*v[j].x + v[j].y*v[j].y + v[j].z*v[j].z + v[j].w*v[j].w;
    }
    #pragma unroll
    for (int o = 32; o > 0; o >>= 1) {
        s += __shfl_xor(s, o); ss += __shfl_xor(ss, o);
    }
    float mean = s * (1.0f/Dz);
    float var  = ss * (1.0f/Dz) - mean*mean;
    float rs = rsqrtf(var + 1e-5f);
    short* yr = y + (long)row*Dz;
    #pragma unroll
    for (int j = 0; j < 3; j++) {
        float4 wj = *(const float4*)(w + lane*4 + j*256);
        float4 bj = *(const float4*)(b + lane*4 + j*256);
        s16x4 pk = { f2b((v[j].x-mean)*rs*wj.x + bj.x),
                     f2b((v[j].y-mean)*rs*wj.y + bj.y),
                     f2b((v[j].z-mean)*rs*wj.z + bj.z),
                     f2b((v[j].w-mean)*rs*wj.w + bj.w) };
        *(s16x4*)(yr + lane*4 + j*256) = pk;
    }
}

// ---------------- loss from fused partials ----------------
__global__ __launch_bounds__(256)
void lossfin_k(const float* __restrict__ logits, const float2* __restrict__ part,
               const int* __restrict__ tgt, float* __restrict__ row_loss)
{
    const int row = blockIdx.x, t = threadIdx.x;
    float m = -3.4e38f, s = 0.f;
    for (int i = t; i < NPART; i += 256) {
        float2 p = part[(long)row*NPART + i];
        float M = fmaxf(m, p.x);
        s = s*__expf(m - M) + p.y*__expf(p.x - M);
        m = M;
    }
    __shared__ float smm[256], sms[256];
    smm[t] = m; sms[t] = s; __syncthreads();
    for (int k = 128; k > 0; k >>= 1) {
        if (t < k) {
            float M = fmaxf(smm[t], smm[t+k]);
            sms[t] = sms[t]*__expf(smm[t]-M) + sms[t+k]*__expf(smm[t+k]-M);
            smm[t] = M;
        }
        __syncthreads();
    }
    if (t == 0)
        row_loss[row] = smm[0] + logf(sms[0]) - logits[(long)row*Vz + tgt[row]];
}

// ---------------- fallback two-pass loss ----------------
__global__ __launch_bounds__(256)
void loss_rows_k(const float* __restrict__ logits, const int* __restrict__ tgt,
                 float* __restrict__ row_loss)
{
    int row = blockIdx.x;
    const float* lr = logits + (long)row*Vz;
    const float4* lr4 = (const float4*)lr;
    int t = threadIdx.x;
    __shared__ float sm[256];
    float mx = -3.4e38f;
    for (int c = t; c < Vz/4; c += 256) {
        float4 f = lr4[c];
        mx = fmaxf(mx, fmaxf(fmaxf(f.x, f.y), fmaxf(f.z, f.w)));
    }
    sm[t] = mx; __syncthreads();
    for (int k = 128; k > 0; k >>= 1) { if (t < k) sm[t] = fmaxf(sm[t], sm[t+k]); __syncthreads(); }
    float m = sm[0]; __syncthreads();
    float s = 0.f;
    for (int c = t; c < Vz/4; c += 256) {
        float4 f = lr4[c];
        s += expf(f.x-m) + expf(f.y-m) + expf(f.z-m) + expf(f.w-m);
    }
    sm[t] = s; __syncthreads();
    for (int k = 128; k > 0; k >>= 1) { if (t < k) sm[t] += sm[t+k]; __syncthreads(); }
    if (t == 0) {
        float logZ = m + logf(sm[0]);
        row_loss[row] = logZ - lr[tgt[row]];
    }
}

__global__ void loss_reduce_k(const float* __restrict__ row_loss, float* __restrict__ out)
{
    __shared__ float sm[256];
    int t = threadIdx.x;
    float s = 0.f;
    for (int i = t; i < BTz; i += 256) s += row_loss[i];
    sm[t] = s; __syncthreads();
    for (int k = 128; k > 0; k >>= 1) { if (t < k) sm[t] += sm[t+k]; __syncthreads(); }
    if (t == 0) out[0] = sm[0] * (1.0f/BTz);
}

// ---------------- host ----------------
extern "C" void kernel_launch(void* const* d_in, const int* in_sizes, int n_in,
                              void* d_out, int out_size, void* d_ws, size_t ws_size,
                              hipStream_t stream)
{
    const int*   idx     = (const int*)  d_in[0];
    const int*   tgt     = (const int*)  d_in[1];
    const float* tok_emb = (const float*)d_in[2];
    const float* pos_emb = (const float*)d_in[3];
    const float* ln1_w   = (const float*)d_in[4];
    const float* ln1_b   = (const float*)d_in[5];
    const float* wq      = (const float*)d_in[6];
    const float* wk      = (const float*)d_in[7];
    const float* wv      = (const float*)d_in[8];
    const float* wo      = (const float*)d_in[9];
    const float* bo      = (const float*)d_in[10];
    const float* ln2_w   = (const float*)d_in[11];
    const float* ln2_b   = (const float*)d_in[12];
    const float* w1      = (const float*)d_in[13];
    const float* b1      = (const float*)d_in[14];
    const float* w2      = (const float*)d_in[15];
    const float* b2      = (const float*)d_in[16];
    const float* lnf_w   = (const float*)d_in[17];
    const float* lnf_b   = (const float*)d_in[18];
    const float* lm_w    = (const float*)d_in[19];
    const float* lm_b    = (const float*)d_in[20];

    float* logits = (float*)d_out;
    float* loss   = logits + (long)BTz*Vz;

    char* p = (char*)d_ws;
    float*  x     = (float*)p;  p += (long)BTz*Dz*4;
    float*  rloss = (float*)p;  p += BTz*4;
    float2* part  = (float2*)p; p += (long)BTz*NPART*8;
    short*  h     = (short*)p;  p += (long)BTz*Dz*2;
    short*  qkvb  = (short*)p;  p += (long)BTz*2304*2;
    short*  attb  = (short*)p;  p += (long)BTz*Dz*2;
    short*  midb  = (short*)p;  p += (long)BTz*DFz*2;
    short*  wall  = (short*)p;
    size_t fixed = (size_t)(p - (char*)d_ws);
    const long LMT = (long)Vz*Dz;                       // 24,576,000
    bool upfront = ws_size >= fixed + (size_t)(8*PLWz + LMT)*2;
    short* lmt = wall + (upfront ? 8*PLWz : PLWz);

    embed_k<<<dim3((BTz*(Dz/4) + 255)/256), 256, 0, stream>>>(idx, tok_emb, pos_emb, x);

    if (upfront) {
        wconv_all<<<dim3(6912, 8), 256, 0, stream>>>(wq, wk, wv, wo, w1, w2, wall, 0);
        tconv_k<<<dim3(Vz/32, 24), 256, 0, stream>>>(lm_w, lmt, Dz, Vz, Vz);
    }

    for (int l = 0; l < Lz; l++) {
        short* wl = wall + (upfront ? (long)l*PLWz : 0);
        if (!upfront)
            wconv_all<<<dim3(6912, 1), 256, 0, stream>>>(wq, wk, wv, wo, w1, w2, wall, l);

        ln_k<<<BTz/4, 256, 0, stream>>>(x, ln1_w + l*Dz, ln1_b + l*Dz, h);
        gemm2<64,0,true><<<dim3(18,32), 256, 0, stream>>>(
            h, wl, nullptr, nullptr, qkvb, Dz, 2304);
        attn_k<<<dim3(Tz/64, Hz, Bz), 256, 0, stream>>>(qkvb, attb);
        gemm2<32,2,false><<<dim3(6,64), 256, 0, stream>>>(
            attb, wl + 1769472, bo + l*Dz, x, x, Dz, Dz);
        ln_k<<<BTz/4, 256, 0, stream>>>(x, ln2_w + l*Dz, ln2_b + l*Dz, h);
        gemm2<64,3,true><<<dim3(24,32), 256, 0, stream>>>(
            h, wl + 2359296, b1 + l*DFz, nullptr, midb, Dz, DFz);
        gemm2<32,2,false><<<dim3(6,64), 256, 0, stream>>>(
            midb, wl + 4718592, b2 + l*Dz, x, x, DFz, Dz);
    }

    ln_k<<<BTz/4, 256, 0, stream>>>(x, lnf_w, lnf_b, h);
    if (upfront) {
        gemm_lm<<<dim3(64, 32), 256, 0, stream>>>(h, lmt, lm_b, logits, part);
        lossfin_k<<<BTz, 256, 0, stream>>>(logits, part, tgt, rloss);
    } else {
        for (int c = 0; c < Vz; c += 8192) {
            int cn = (Vz - c < 8192) ? (Vz - c) : 8192;
            tconv_k<<<dim3(cn/32, 24), 256, 0, stream>>>(lm_w + c, lmt, Dz, cn, Vz);
            gemm2<128,1,false><<<dim3(cn/128, 16), 256, 0, stream>>>(
                h, lmt, lm_b + c, nullptr, logits + c, Dz, Vz);
        }
        loss_rows_k<<<BTz, 256, 0, stream>>>(logits, tgt, rloss);
    }
    loss_reduce_k<<<1, 256, 0, stream>>>(rloss, loss);
}

// Round 17
// 1596.399 us; speedup vs baseline: 1.0855x; 1.0088x over previous
//
#include <hip/hip_runtime.h>

#define Bz   2
#define Tz   1024
#define Dz   768
#define Hz   12
#define HDz  64
#define Lz   8
#define Vz   32000
#define BTz  (Bz*Tz)       // 2048
#define DFz  (4*Dz)        // 3072
#define PLWz 7077888L      // bf16 elems per layer weight slot
#define NPART 500          // loss partials per row: 250 col-blocks * 2 waves
#define SCALEz 0.036084391824351615f  // 768^-0.5 (reference uses D^-0.5)

typedef __attribute__((ext_vector_type(4))) short s16x4;
typedef __attribute__((ext_vector_type(8))) short s16x8;
typedef __attribute__((ext_vector_type(4))) float f32x4;

__device__ __forceinline__ short f2b(float f) {  // f32 -> bf16 RNE
    union { float f; unsigned u; } v; v.f = f;
    unsigned r = v.u + 0x7fffu + ((v.u >> 16) & 1u);
    return (short)(r >> 16);
}

__device__ __forceinline__ void gload16(const short* g, short* l) {
    __builtin_amdgcn_global_load_lds(
        (const __attribute__((address_space(1))) void*)g,
        (__attribute__((address_space(3))) void*)l, 16, 0, 0);
}

#define MFMA32(a,b,c) __builtin_amdgcn_mfma_f32_16x16x32_bf16(a,b,c,0,0,0)

// ---------------- transpose-convert: f32 [K][N](ldin) -> bf16 [N][K] ----------------
__global__ __launch_bounds__(256)
void tconv_k(const float* __restrict__ in, short* __restrict__ out,
             int K, int N, int ldin)
{
    __shared__ float tl[32][33];
    const int tx = threadIdx.x & 31, ty = threadIdx.x >> 5;
    const int n0 = blockIdx.x * 32, k0 = blockIdx.y * 32;
    #pragma unroll
    for (int i = 0; i < 4; i++)
        tl[ty + i*8][tx] = in[(long)(k0 + ty + i*8)*ldin + n0 + tx];
    __syncthreads();
    #pragma unroll
    for (int i = 0; i < 4; i++)
        out[(long)(n0 + ty + i*8)*K + k0 + tx] = f2b(tl[tx][ty + i*8]);
}

// ---------------- all per-layer weights, one launch ----------------
__global__ __launch_bounds__(256)
void wconv_all(const float* __restrict__ wq, const float* __restrict__ wk,
               const float* __restrict__ wv, const float* __restrict__ wo,
               const float* __restrict__ w1, const float* __restrict__ w2,
               short* __restrict__ wall, int l0)
{
    const int l = l0 + blockIdx.y;
    short* dst = wall + (long)blockIdx.y * PLWz;
    int t = blockIdx.x;
    const float* src; long doff; int K, N, ldin, nx;
    if (t < 2304) {
        int m = t / 576; t -= m * 576;
        src = (m==0 ? wq : m==1 ? wk : m==2 ? wv : wo) + (long)l * 589824;
        doff = (long)m * 589824; K = 768; N = 768; ldin = 768; nx = 24;
    } else if (t < 4608) {
        t -= 2304;
        src = w1 + (long)l * 2359296; doff = 2359296; K = 768; N = 3072; ldin = 3072; nx = 96;
    } else {
        t -= 4608;
        src = w2 + (long)l * 2359296; doff = 4718592; K = 3072; N = 768; ldin = 768; nx = 24;
    }
    const int n0 = (t % nx) * 32, k0 = (t / nx) * 32;
    __shared__ float tl[32][33];
    const int tx = threadIdx.x & 31, ty = threadIdx.x >> 5;
    #pragma unroll
    for (int i = 0; i < 4; i++)
        tl[ty + i*8][tx] = src[(long)(k0 + ty + i*8)*ldin + n0 + tx];
    __syncthreads();
    short* o = dst + doff;
    #pragma unroll
    for (int i = 0; i < 4; i++)
        o[(long)(n0 + ty + i*8)*K + k0 + tx] = f2b(tl[tx][ty + i*8]);
}

// ---------------- generic bf16 GEMM (per-layer), 2-phase double-buffered ----------------
// C[M,N] = epi( A[M,K] @ Bt[N,K]^T ). EPI: 0 none | 1 +bias | 2 +bias+res(f32) | 3 +bias,GELU
template<int BM, int EPI, bool OUTBF>
__global__ __launch_bounds__(256)
void gemm2(const short* __restrict__ A, const short* __restrict__ Bt,
           const float* __restrict__ bias, const float* __restrict__ resp,
           void* __restrict__ Cv, int K, int ldc)
{
    constexpr int BN = 128, BK = 64;
    constexpr int WTM = BM/2;
    constexpr int AM = WTM/16;
    __shared__ short Al[2][BM*BK];
    __shared__ short Bl[2][BN*BK];
    const int bx = blockIdx.x, by = blockIdx.y;
    const int m0 = by*BM, n0 = bx*BN;
    const int tid = threadIdx.x, lane = tid & 63, wid = tid >> 6;
    const int wm = wid >> 1, wn = wid & 1;
    const int r = lane & 15, kg = lane >> 4;
    const int arow = lane >> 3, acol = (lane & 7)*8;

    const short* ga = A  + (long)(m0 + wid*(BM/4) + arow)*K + acol;
    const short* gb = Bt + (long)(n0 + wid*32     + arow)*K + acol;
    const int laoff = (wid*(BM/4))*BK;
    const int lboff = (wid*32)*BK;

    auto stage = [&](int buf, int k0) {
        short* la = &Al[buf][laoff];
        short* lb = &Bl[buf][lboff];
        #pragma unroll
        for (int i = 0; i < BM/32; i++)
            gload16(ga + (long)i*8*K + k0, la + i*8*BK);
        #pragma unroll
        for (int i = 0; i < 4; i++)
            gload16(gb + (long)i*8*K + k0, lb + i*8*BK);
    };

    f32x4 acc[AM][4] = {};
    const int nk = K / BK;

    stage(0, 0);
    __syncthreads();
    int cur = 0;
    for (int t = 0; t < nk; t++) {
        if (t + 1 < nk) stage(cur ^ 1, (t + 1)*BK);
        #pragma unroll
        for (int ks = 0; ks < 2; ks++) {
            s16x8 af[AM], bf[4];
            #pragma unroll
            for (int mI = 0; mI < AM; mI++)
                af[mI] = *(const s16x8*)&Al[cur][(wm*WTM + mI*16 + r)*BK + ks*32 + kg*8];
            #pragma unroll
            for (int nI = 0; nI < 4; nI++)
                bf[nI] = *(const s16x8*)&Bl[cur][(wn*64 + nI*16 + r)*BK + ks*32 + kg*8];
            #pragma unroll
            for (int mI = 0; mI < AM; mI++)
                #pragma unroll
                for (int nI = 0; nI < 4; nI++)
                    acc[mI][nI] = MFMA32(af[mI], bf[nI], acc[mI][nI]);
        }
        __syncthreads();
        cur ^= 1;
    }

    float bnv[4] = {0.f, 0.f, 0.f, 0.f};
    if constexpr (EPI >= 1) {
        #pragma unroll
        for (int nI = 0; nI < 4; nI++) bnv[nI] = bias[n0 + wn*64 + nI*16 + r];
    }

    #pragma unroll
    for (int mI = 0; mI < AM; mI++) {
        #pragma unroll
        for (int nI = 0; nI < 4; nI++) {
            #pragma unroll
            for (int reg = 0; reg < 4; reg++) {
                int row = wm*WTM + mI*16 + kg*4 + reg;
                int col = wn*64 + nI*16 + r;
                long off = (long)(m0+row)*ldc + (n0+col);
                float v = acc[mI][nI][reg] + bnv[nI];
                if constexpr (EPI == 2) v += resp[off];
                if constexpr (EPI == 3) v = 0.5f*v*(1.0f + erff(v*0.70710678118654752f));
                if constexpr (OUTBF) ((short*)Cv)[off] = f2b(v);
                else                 ((float*)Cv)[off] = v;
            }
        }
    }
}

// ---------------- LM-head GEMM: BM=256xBN=128, XCD-pinned, fused loss; 3 blocks/CU ----
__global__ __launch_bounds__(256, 3)
void gemm_lm(const short* __restrict__ A, const short* __restrict__ Bt,
             const float* __restrict__ bias, float* __restrict__ C,
             float2* __restrict__ part)
{
    constexpr int BM = 256, BN = 128, BK = 64;
    const int b8 = blockIdx.x & 7, rr = blockIdx.x >> 3;   // rr: row-block 0..7
    const int c  = blockIdx.y * 8 + b8;                    // col-block
    if (c >= Vz/BN) return;
    const int m0 = rr * BM, n0 = c * BN;
    const int K = Dz;
    __shared__ short Al[BM*BK];   // 32 KB
    __shared__ short Bl[BN*BK];   // 16 KB
    const int tid = threadIdx.x, lane = tid & 63, wid = tid >> 6;
    const int wm = wid >> 1, wn = wid & 1;
    const int r = lane & 15, kg = lane >> 4;
    const int arow = lane >> 3, acol = (lane & 7)*8;

    const short* ga = A  + (long)(m0 + wid*64 + arow)*K + acol;
    const short* gb = Bt + (long)(n0 + wid*32 + arow)*K + acol;
    short* la = &Al[(wid*64)*BK];
    short* lb = &Bl[(wid*32)*BK];

    f32x4 acc[8][4] = {};

    for (int k0 = 0; k0 < K; k0 += BK) {
        #pragma unroll
        for (int i = 0; i < 8; i++)
            gload16(ga + (long)i*8*K + k0, la + i*8*BK);
        #pragma unroll
        for (int i = 0; i < 4; i++)
            gload16(gb + (long)i*8*K + k0, lb + i*8*BK);
        __syncthreads();
        #pragma unroll
        for (int ks = 0; ks < 2; ks++) {
            s16x8 bf[4];
            #pragma unroll
            for (int nI = 0; nI < 4; nI++)
                bf[nI] = *(const s16x8*)&Bl[(wn*64 + nI*16 + r)*BK + ks*32 + kg*8];
            #pragma unroll
            for (int mI = 0; mI < 8; mI++) {
                s16x8 af = *(const s16x8*)&Al[(wm*128 + mI*16 + r)*BK + ks*32 + kg*8];
                #pragma unroll
                for (int nI = 0; nI < 4; nI++)
                    acc[mI][nI] = MFMA32(af, bf[nI], acc[mI][nI]);
            }
        }
        __syncthreads();
    }

    float bnv[4];
    #pragma unroll
    for (int nI = 0; nI < 4; nI++) bnv[nI] = bias[n0 + wn*64 + nI*16 + r];

    #pragma unroll
    for (int mI = 0; mI < 8; mI++) {
        #pragma unroll
        for (int nI = 0; nI < 4; nI++) {
            #pragma unroll
            for (int reg = 0; reg < 4; reg++) {
                int row = wm*128 + mI*16 + kg*4 + reg;
                int col = wn*64 + nI*16 + r;
                C[(long)(m0+row)*Vz + (n0+col)] = acc[mI][nI][reg] + bnv[nI];
            }
        }
        #pragma unroll
        for (int reg = 0; reg < 4; reg++) {
            float mx = -3.4e38f;
            #pragma unroll
            for (int nI = 0; nI < 4; nI++)
                mx = fmaxf(mx, acc[mI][nI][reg] + bnv[nI]);
            #pragma unroll
            for (int o = 1; o < 16; o <<= 1)
                mx = fmaxf(mx, __shfl_xor(mx, o));
            float s = 0.f;
            #pragma unroll
            for (int nI = 0; nI < 4; nI++)
                s += __expf(acc[mI][nI][reg] + bnv[nI] - mx);
            #pragma unroll
            for (int o = 1; o < 16; o <<= 1)
                s += __shfl_xor(s, o);
            if (r == 0) {
                int row = m0 + wm*128 + mI*16 + kg*4 + reg;
                part[(long)row*NPART + c*2 + wn] = make_float2(mx, s);
            }
        }
    }
}

// ---------------- fused flash attention (scalar-V, proven round-8 optimum) ----------------
__global__ __launch_bounds__(256)
void attn_k(const short* __restrict__ qkv, short* __restrict__ att)
{
    const int w = threadIdx.x >> 6;
    const int lane = threadIdx.x & 63;
    const int r = lane & 15, kg = lane >> 4;
    const int hd0 = blockIdx.y * HDz;
    const long brow = (long)blockIdx.z * Tz;
    const int q0w = blockIdx.x * 64 + w * 16;
    const int qi = q0w + r;

    const short* qp = qkv + (brow + q0w + r) * 2304 + hd0;
    const s16x8 qf0 = *(const s16x8*)(qp + kg*8);
    const s16x8 qf1 = *(const s16x8*)(qp + 32 + kg*8);
    const short* kb = qkv + brow * 2304 + 768 + hd0;
    const short* vb = qkv + brow * 2304 + 1536 + hd0;

    float m = -3.4e38f, l = 0.f;
    f32x4 ot[4] = {};

    const int ntiles = blockIdx.x * 4 + w + 1;
    for (int t = 0; t < ntiles; t++) {
        const int kt = t * 16;
        const short* kp = kb + (long)(kt + r) * 2304;
        s16x8 kf0 = *(const s16x8*)(kp + kg*8);
        s16x8 kf1 = *(const s16x8*)(kp + 32 + kg*8);
        f32x4 z = {};
        f32x4 st = MFMA32(kf0, qf0, z);   // S^T: row=key kt+kg*4+reg, col=q q0w+r
        st = MFMA32(kf1, qf1, st);
        float s4[4];
        #pragma unroll
        for (int j = 0; j < 4; j++) {
            int ki = kt + kg*4 + j;
            s4[j] = (ki <= qi) ? st[j]*SCALEz : -1e30f;
        }
        float cm = fmaxf(fmaxf(s4[0], s4[1]), fmaxf(s4[2], s4[3]));
        cm = fmaxf(cm, __shfl_xor(cm, 16));
        cm = fmaxf(cm, __shfl_xor(cm, 32));
        float mn = fmaxf(m, cm);
        float alpha = __expf(m - mn);
        float p0 = __expf(s4[0]-mn), p1 = __expf(s4[1]-mn);
        float p2 = __expf(s4[2]-mn), p3 = __expf(s4[3]-mn);
        l = l*alpha + (p0+p1+p2+p3);
        m = mn;
        s16x8 pb = { f2b(p0), f2b(p1), f2b(p2), f2b(p3), 0, 0, 0, 0 };
        #pragma unroll
        for (int d0 = 0; d0 < 4; d0++) {
            const short* vp = vb + (long)(kt + kg*4)*2304 + d0*16 + r;
            s16x8 va = { vp[0], vp[2304], vp[4608], vp[6912], 0, 0, 0, 0 };
            f32x4 o = ot[d0];
            o[0]*=alpha; o[1]*=alpha; o[2]*=alpha; o[3]*=alpha;
            ot[d0] = MFMA32(va, pb, o);   // O^T: row d=kg*4+reg, col q=r
        }
    }
    l += __shfl_xor(l, 16);
    l += __shfl_xor(l, 32);
    const float inv = 1.f / l;
    short* ap = att + (brow + q0w + r)*Dz + hd0;
    #pragma unroll
    for (int d0 = 0; d0 < 4; d0++) {
        s16x4 pk = { f2b(ot[d0][0]*inv), f2b(ot[d0][1]*inv),
                     f2b(ot[d0][2]*inv), f2b(ot[d0][3]*inv) };
        *(s16x4*)(ap + d0*16 + kg*4) = pk;
    }
}

// ---------------- embedding ----------------
__global__ void embed_k(const int* __restrict__ idx, const float* __restrict__ tok,
                        const float* __restrict__ pos, float* __restrict__ x)
{
    int qi = blockIdx.x*blockDim.x + threadIdx.x;
    if (qi >= BTz*(Dz/4)) return;
    int row = qi / (Dz/4);
    int c   = (qi % (Dz/4)) * 4;
    int token = idx[row];
    int tpos  = row & (Tz-1);
    float4 a = *reinterpret_cast<const float4*>(tok + (long)token*Dz + c);
    float4 p = *reinterpret_cast<const float4*>(pos + (long)tpos*Dz + c);
    float4 o; o.x=a.x+p.x; o.y=a.y+p.y; o.z=a.z+p.z; o.w=a.w+p.w;
    *reinterpret_cast<float4*>(x + (long)row*Dz + c) = o;
}

// ---------------- layernorm: wave per row, f32 in, bf16 out ----------------
__global__ __launch_bounds__(256)
void ln_k(const float* __restrict__ x, const float* __restrict__ w,
          const float* __restrict__ b, short* __restrict__ y)
{
    const int lane = threadIdx.x & 63;
    const int row = blockIdx.x*4 + (threadIdx.x >> 6);
    const float* xr = x + (long)row*Dz;
    float4 v[3];
    #pragma unroll
    for (int j = 0; j < 3; j++) v[j] = *(const float4*)(xr + lane*4 + j*256);
    float s = 0.f, ss = 0.f;
    #pragma unroll
    for (int j = 0; j < 3; j++) {
        s  += v[j].x + v[j].y + v[j].z + v[j].w;
        ss += v[j].x*v[j].x + v[j].y*v[j].y + v[j].z*v[j].z + v[j].w*v[j].w;
    }
    #pragma unroll
    for (int o = 32; o > 0; o >>= 1) {
        s += __shfl_xor(s, o); ss += __shfl_xor(ss, o);
    }
    float mean = s * (1.0f/Dz);
    float var  = ss * (1.0f/Dz) - mean*mean;
    float rs = rsqrtf(var + 1e-5f);
    short* yr = y + (long)row*Dz;
    #pragma unroll
    for (int j = 0; j < 3; j++) {
        float4 wj = *(const float4*)(w + lane*4 + j*256);
        float4 bj = *(const float4*)(b + lane*4 + j*256);
        s16x4 pk = { f2b((v[j].x-mean)*rs*wj.x + bj.x),
                     f2b((v[j].y-mean)*rs*wj.y + bj.y),
                     f2b((v[j].z-mean)*rs*wj.z + bj.z),
                     f2b((v[j].w-mean)*rs*wj.w + bj.w) };
        *(s16x4*)(yr + lane*4 + j*256) = pk;
    }
}

// ---------------- loss from fused partials ----------------
__global__ __launch_bounds__(256)
void lossfin_k(const float* __restrict__ logits, const float2* __restrict__ part,
               const int* __restrict__ tgt, float* __restrict__ row_loss)
{
    const int row = blockIdx.x, t = threadIdx.x;
    float m = -3.4e38f, s = 0.f;
    for (int i = t; i < NPART; i += 256) {
        float2 p = part[(long)row*NPART + i];
        float M = fmaxf(m, p.x);
        s = s*__expf(m - M) + p.y*__expf(p.x - M);
        m = M;
    }
    __shared__ float smm[256], sms[256];
    smm[t] = m; sms[t] = s; __syncthreads();
    for (int k = 128; k > 0; k >>= 1) {
        if (t < k) {
            float M = fmaxf(smm[t], smm[t+k]);
            sms[t] = sms[t]*__expf(smm[t]-M) + sms[t+k]*__expf(smm[t+k]-M);
            smm[t] = M;
        }
        __syncthreads();
    }
    if (t == 0)
        row_loss[row] = smm[0] + logf(sms[0]) - logits[(long)row*Vz + tgt[row]];
}

// ---------------- fallback two-pass loss ----------------
__global__ __launch_bounds__(256)
void loss_rows_k(const float* __restrict__ logits, const int* __restrict__ tgt,
                 float* __restrict__ row_loss)
{
    int row = blockIdx.x;
    const float* lr = logits + (long)row*Vz;
    const float4* lr4 = (const float4*)lr;
    int t = threadIdx.x;
    __shared__ float sm[256];
    float mx = -3.4e38f;
    for (int c = t; c < Vz/4; c += 256) {
        float4 f = lr4[c];
        mx = fmaxf(mx, fmaxf(fmaxf(f.x, f.y), fmaxf(f.z, f.w)));
    }
    sm[t] = mx; __syncthreads();
    for (int k = 128; k > 0; k >>= 1) { if (t < k) sm[t] = fmaxf(sm[t], sm[t+k]); __syncthreads(); }
    float m = sm[0]; __syncthreads();
    float s = 0.f;
    for (int c = t; c < Vz/4; c += 256) {
        float4 f = lr4[c];
        s += expf(f.x-m) + expf(f.y-m) + expf(f.z-m) + expf(f.w-m);
    }
    sm[t] = s; __syncthreads();
    for (int k = 128; k > 0; k >>= 1) { if (t < k) sm[t] += sm[t+k]; __syncthreads(); }
    if (t == 0) {
        float logZ = m + logf(sm[0]);
        row_loss[row] = logZ - lr[tgt[row]];
    }
}

__global__ void loss_reduce_k(const float* __restrict__ row_loss, float* __restrict__ out)
{
    __shared__ float sm[256];
    int t = threadIdx.x;
    float s = 0.f;
    for (int i = t; i < BTz; i += 256) s += row_loss[i];
    sm[t] = s; __syncthreads();
    for (int k = 128; k > 0; k >>= 1) { if (t < k) sm[t] += sm[t+k]; __syncthreads(); }
    if (t == 0) out[0] = sm[0] * (1.0f/BTz);
}

// ---------------- host ----------------
extern "C" void kernel_launch(void* const* d_in, const int* in_sizes, int n_in,
                              void* d_out, int out_size, void* d_ws, size_t ws_size,
                              hipStream_t stream)
{
    const int*   idx     = (const int*)  d_in[0];
    const int*   tgt     = (const int*)  d_in[1];
    const float* tok_emb = (const float*)d_in[2];
    const float* pos_emb = (const float*)d_in[3];
    const float* ln1_w   = (const float*)d_in[4];
    const float* ln1_b   = (const float*)d_in[5];
    const float* wq      = (const float*)d_in[6];
    const float* wk      = (const float*)d_in[7];
    const float* wv      = (const float*)d_in[8];
    const float* wo      = (const float*)d_in[9];
    const float* bo      = (const float*)d_in[10];
    const float* ln2_w   = (const float*)d_in[11];
    const float* ln2_b   = (const float*)d_in[12];
    const float* w1      = (const float*)d_in[13];
    const float* b1      = (const float*)d_in[14];
    const float* w2      = (const float*)d_in[15];
    const float* b2      = (const float*)d_in[16];
    const float* lnf_w   = (const float*)d_in[17];
    const float* lnf_b   = (const float*)d_in[18];
    const float* lm_w    = (const float*)d_in[19];
    const float* lm_b    = (const float*)d_in[20];

    float* logits = (float*)d_out;
    float* loss   = logits + (long)BTz*Vz;

    char* p = (char*)d_ws;
    float*  x     = (float*)p;  p += (long)BTz*Dz*4;
    float*  rloss = (float*)p;  p += BTz*4;
    float2* part  = (float2*)p; p += (long)BTz*NPART*8;
    short*  h     = (short*)p;  p += (long)BTz*Dz*2;
    short*  qkvb  = (short*)p;  p += (long)BTz*2304*2;
    short*  attb  = (short*)p;  p += (long)BTz*Dz*2;
    short*  midb  = (short*)p;  p += (long)BTz*DFz*2;
    short*  wall  = (short*)p;
    size_t fixed = (size_t)(p - (char*)d_ws);
    const long LMT = (long)Vz*Dz;                       // 24,576,000
    bool upfront = ws_size >= fixed + (size_t)(8*PLWz + LMT)*2;
    short* lmt = wall + (upfront ? 8*PLWz : PLWz);

    embed_k<<<dim3((BTz*(Dz/4) + 255)/256), 256, 0, stream>>>(idx, tok_emb, pos_emb, x);

    if (upfront) {
        wconv_all<<<dim3(6912, 8), 256, 0, stream>>>(wq, wk, wv, wo, w1, w2, wall, 0);
        tconv_k<<<dim3(Vz/32, 24), 256, 0, stream>>>(lm_w, lmt, Dz, Vz, Vz);
    }

    for (int l = 0; l < Lz; l++) {
        short* wl = wall + (upfront ? (long)l*PLWz : 0);
        if (!upfront)
            wconv_all<<<dim3(6912, 1), 256, 0, stream>>>(wq, wk, wv, wo, w1, w2, wall, l);

        ln_k<<<BTz/4, 256, 0, stream>>>(x, ln1_w + l*Dz, ln1_b + l*Dz, h);
        gemm2<64,0,true><<<dim3(18,32), 256, 0, stream>>>(
            h, wl, nullptr, nullptr, qkvb, Dz, 2304);
        attn_k<<<dim3(Tz/64, Hz, Bz), 256, 0, stream>>>(qkvb, attb);
        gemm2<32,2,false><<<dim3(6,64), 256, 0, stream>>>(
            attb, wl + 1769472, bo + l*Dz, x, x, Dz, Dz);
        ln_k<<<BTz/4, 256, 0, stream>>>(x, ln2_w + l*Dz, ln2_b + l*Dz, h);
        gemm2<64,3,true><<<dim3(24,32), 256, 0, stream>>>(
            h, wl + 2359296, b1 + l*DFz, nullptr, midb, Dz, DFz);
        gemm2<32,2,false><<<dim3(6,64), 256, 0, stream>>>(
            midb, wl + 4718592, b2 + l*Dz, x, x, DFz, Dz);
    }

    ln_k<<<BTz/4, 256, 0, stream>>>(x, lnf_w, lnf_b, h);
    if (upfront) {
        gemm_lm<<<dim3(64, 32), 256, 0, stream>>>(h, lmt, lm_b, logits, part);
        lossfin_k<<<BTz, 256, 0, stream>>>(logits, part, tgt, rloss);
    } else {
        for (int c = 0; c < Vz; c += 8192) {
            int cn = (Vz - c < 8192) ? (Vz - c) : 8192;
            tconv_k<<<dim3(cn/32, 24), 256, 0, stream>>>(lm_w + c, lmt, Dz, cn, Vz);
            gemm2<128,1,false><<<dim3(cn/128, 16), 256, 0, stream>>>(
                h, lmt, lm_b + c, nullptr, logits + c, Dz, Vz);
        }
        loss_rows_k<<<BTz, 256, 0, stream>>>(logits, tgt, rloss);
    }
    loss_reduce_k<<<1, 256, 0, stream>>>(rloss, loss);
}